// Round 12
// baseline (178.959 us; speedup 1.0000x reference)
//
#include <hip/hip_runtime.h>
#include <hip/hip_bf16.h>

typedef __bf16 bf16_t;
typedef __bf16 bf16x4 __attribute__((ext_vector_type(4)));
typedef __bf16 bf16x8 __attribute__((ext_vector_type(8)));
typedef float  f32x4  __attribute__((ext_vector_type(4)));
typedef float  f32x8  __attribute__((ext_vector_type(8)));
typedef unsigned int u32;
typedef u32 u32x4 __attribute__((ext_vector_type(4)));

#define EMBED 512
#define NH    8
#define HD    64
#define SEQ   2048
#define MTOT  8192
#define SCQ   0.18033688011112042f   // log2(e) / sqrt(64), folded into Q

__device__ __forceinline__ float gelu_f(float x) {
    return 0.5f * x * (1.0f + erff(x * 0.7071067811865475f));
}

__device__ __forceinline__ f32x4 mfma16(bf16x8 a, bf16x8 b, f32x4 c) {
    return __builtin_amdgcn_mfma_f32_16x16x32_bf16(a, b, c, 0, 0, 0);
}

// Raw barrier: LDS-write visibility only (lgkmcnt(0)), NO vmcnt drain —
// global prefetch loads stay in flight across the barrier; the compiler
// emits counted vmcnt waits at the dependent use.
__device__ __forceinline__ void barrier_nodrain() {
    asm volatile("s_waitcnt lgkmcnt(0)" ::: "memory");
    __builtin_amdgcn_s_barrier();
    asm volatile("" ::: "memory");
}

// Single-instruction exp2 (R10/R11-proven: flash 68.4 -> 52.6 µs; scores are
// O(1) so no libm range fixup needed).
__device__ __forceinline__ float fast_exp2(float x) {
    float r;
    asm("v_exp_f32 %0, %1" : "=v"(r) : "v"(x));
    return r;
}

// T12 primitives (flash): pack 2 f32 -> 2 bf16, cross-lane register swaps.
__device__ __forceinline__ u32 cvtpk_bf16(float lo, float hi) {
    u32 r;
    asm("v_cvt_pk_bf16_f32 %0, %1, %2" : "=v"(r) : "v"(lo), "v"(hi));
    return r;
}
__device__ __forceinline__ void swap32(u32& a, u32& b) {
    asm volatile("v_permlane32_swap_b32 %0, %1" : "+v"(a), "+v"(b));
}
__device__ __forceinline__ void swap16(u32& a, u32& b) {
    asm volatile("v_permlane16_swap_b32 %0, %1" : "+v"(a), "+v"(b));
}

// ---------------------------------------------------------------------------
// GEMM + bias + GELU.  C[m][n] = gelu( sum_k X[m][k]*W[n][k] + bias[n] )
//
// R12: ping-pong LDS, ONE barrier per K-step. At step kt the ds_writes for
// tile kt+1 target buf^1 WHILE the MFMA phase reads buf — staging leaves
// the intra-block serial chain (the term none of R5-R10's variants removed:
// they all had stage -> barrier -> compute serialized). Barriers 16 -> 8.
// Global loads issue 2 tiles ahead; counted vmcnt at the ds_write gives a
// full K-step of latency cover. Correctness: writes to buf^1 at kt are
// WAR-guarded by the barrier at kt-1 (buf^1 last read at kt-1); reads at
// kt+1 see the writes via lgkmcnt(0)+barrier at kt.
// LDS 73.7KB (MODE1 55.3KB) -> 2 blocks/CU — occupancy thrice proven a
// non-lever (R4/R10). VGPR ~160 < 256 @ (256,2).
// Fused fp32 convert kept from R8/R11 (x and W read fp32, convert at write).
// ---------------------------------------------------------------------------
template<int MODE, int NTILE>
__global__ __launch_bounds__(256, 2)
void gemm_gelu_kernel(const void*  __restrict__ Xp,
                      const float* __restrict__ W0, const float* __restrict__ W1,
                      const float* __restrict__ W2,
                      const float* __restrict__ Bq, const float* __restrict__ Bk,
                      const float* __restrict__ Bv,
                      bf16_t* __restrict__ O0, bf16_t* __restrict__ O1,
                      bf16_t* __restrict__ O2, float* __restrict__ Of)
{
    constexpr int NTN = NTILE / 32;   // B-staging iters/thr
    __shared__ __align__(16) bf16_t As[2][128 * 72];
    __shared__ __align__(16) bf16_t Bs[2][NTILE * 72];
    const int tid  = threadIdx.x;
    const int lane = tid & 63, w = tid >> 6, quad = lane >> 4, l15 = lane & 15;
    const int m0 = blockIdx.x * 128;
    int mat, n0;
    if (MODE == 0) { mat = blockIdx.y >> 2; n0 = (blockIdx.y & 3) * NTILE; }
    else           { mat = 0;               n0 = blockIdx.y * NTILE; }
    const float* W  = (MODE == 0) ? (mat == 0 ? W0 : (mat == 1 ? W1 : W2)) : W0;
    const float* Bi = (MODE == 1) ? Bq : (mat == 0 ? Bq : (mat == 1 ? Bk : Bv));
    const float*  Xf = (const float*)Xp;    // MODE 0
    const bf16_t* Xb = (const bf16_t*)Xp;   // MODE 1

    const int wr = (w >> 1) * 64;            // wave row offset
    const int wc = (w & 1) * (NTILE / 2);    // wave col offset

    const int srow = tid >> 3, scol = (tid & 7) * 8;

    f32x4 acc[4][NTN];
#pragma unroll
    for (int a = 0; a < 4; ++a)
#pragma unroll
        for (int b = 0; b < NTN; ++b) acc[a][b] = f32x4{0.f, 0.f, 0.f, 0.f};

    f32x8  xaf[4];   // MODE 0 A regs (fp32)
    bf16x8 xab[4];   // MODE 1 A regs (bf16)
    f32x8  wpf[NTN]; // W regs (fp32)

    // load tile kt's A/W into regs
    auto load_tile = [&](int kt) {
        const int k0 = kt * 64;
#pragma unroll
        for (int it = 0; it < 4; ++it) {
            const size_t r = (size_t)(m0 + it * 32 + srow);
            if (MODE == 0) xaf[it] = *(const f32x8*)(Xf + r * EMBED + k0 + scol);
            else           xab[it] = *(const bf16x8*)(Xb + r * EMBED + k0 + scol);
        }
#pragma unroll
        for (int it = 0; it < NTN; ++it) {
            const int r = it * 32 + srow;
            wpf[it] = *(const f32x8*)(W + (size_t)(n0 + r) * EMBED + k0 + scol);
        }
    };
    // write regs into buffer buf
    auto write_tile = [&](int buf) {
#pragma unroll
        for (int it = 0; it < 4; ++it) {
            if (MODE == 0)
                *(bf16x8*)(&As[buf][(it * 32 + srow) * 72 + scol]) =
                    __builtin_convertvector(xaf[it], bf16x8);
            else
                *(bf16x8*)(&As[buf][(it * 32 + srow) * 72 + scol]) = xab[it];
        }
#pragma unroll
        for (int it = 0; it < NTN; ++it) {
            const int r = it * 32 + srow;
            *(bf16x8*)(&Bs[buf][r * 72 + scol]) =
                __builtin_convertvector(wpf[it], bf16x8);
        }
    };

    // prologue: tile0 -> regs -> buf0; tile1 -> regs; publish buf0
    load_tile(0);
    write_tile(0);
    load_tile(1);
    barrier_nodrain();

#pragma unroll 1
    for (int kt = 0; kt < 8; ++kt) {
        const int cb = kt & 1;
        // stage tile kt+1 into buf^1 (concurrent with compute below)
        if (kt < 7) write_tile(cb ^ 1);
        // prefetch tile kt+2 into regs (consumed next step)
        if (kt < 6) load_tile(kt + 2);
        // compute from buf cb
        const bf16_t* Ab = As[cb];
        const bf16_t* Bb = Bs[cb];
#pragma unroll
        for (int ks = 0; ks < 2; ++ks) {
            const int ko = (ks * 4 + quad) * 8;
            bf16x8 av[4], bv[NTN];
#pragma unroll
            for (int mt = 0; mt < 4; ++mt)
                av[mt] = *(const bf16x8*)(Ab + (wr + mt * 16 + l15) * 72 + ko);
#pragma unroll
            for (int nt = 0; nt < NTN; ++nt)
                bv[nt] = *(const bf16x8*)(Bb + (wc + nt * 16 + l15) * 72 + ko);
#pragma unroll
            for (int mt = 0; mt < 4; ++mt)
#pragma unroll
                for (int nt = 0; nt < NTN; ++nt)
                    acc[mt][nt] = mfma16(av[mt], bv[nt], acc[mt][nt]);
        }
        // one barrier per step: publishes buf^1 writes, guards buf reuse
        if (kt < 7) barrier_nodrain();
    }

    // epilogue (C/D layout: col=l15, row=quad*4+i)
    float biasv[NTN];
#pragma unroll
    for (int nt = 0; nt < NTN; ++nt)
        biasv[nt] = Bi[n0 + wc + nt * 16 + l15];
#pragma unroll
    for (int mt = 0; mt < 4; ++mt) {
        const int mb = m0 + wr + mt * 16 + quad * 4;
        const int bb = mb >> 11, s0 = mb & (SEQ - 1);
#pragma unroll
        for (int nt = 0; nt < NTN; ++nt) {
            const int fc = n0 + wc + nt * 16 + l15;
            const int h = fc >> 6, d = fc & 63;
            float vv[4];
#pragma unroll
            for (int i = 0; i < 4; ++i) vv[i] = gelu_f(acc[mt][nt][i] + biasv[nt]);
            if (MODE == 1) {
#pragma unroll
                for (int i = 0; i < 4; ++i) Of[(size_t)(mb + i) * EMBED + fc] = vv[i];
            } else if (mat == 0) {
#pragma unroll
                for (int i = 0; i < 4; ++i)
                    O0[(((size_t)(bb * NH + h)) * SEQ + s0 + i) * HD + d] = (bf16_t)(vv[i] * SCQ);
            } else if (mat == 1) {
#pragma unroll
                for (int i = 0; i < 4; ++i)
                    O1[(((size_t)(bb * NH + h)) * SEQ + s0 + i) * HD + d] = (bf16_t)vv[i];
            } else {
                bf16x4 pk;
#pragma unroll
                for (int i = 0; i < 4; ++i) pk[i] = (bf16_t)vv[i];
                *(bf16x4*)(O2 + ((size_t)(bb * NH + h) * HD + d) * SEQ + s0) = pk;
            }
        }
    }
}

// ---------------------------------------------------------------------------
// Flash attention — UNCHANGED from R11 (52.6 µs, conflicts 0, T12 in-reg P,
// fast_exp2, nodrain barriers, 2-tile-deep A/B register prefetch).
// ---------------------------------------------------------------------------
#define FA_ITER(T, BUF, KR0, KR1, VR0, VR1)                                   \
    do {                                                                      \
        if ((T) + 1 < 32) {                                                   \
            bf16_t* Kn = Ks[(BUF) ^ 1];                                       \
            bf16_t* Vn = Vs[(BUF) ^ 1];                                       \
            *(bf16x8*)(Kn + sA)        = KR0;                                 \
            *(bf16x8*)(Kn + sA + 2048) = KR1;                                 \
            *(bf16x8*)(Vn + sA)        = VR0;                                 \
            *(bf16x8*)(Vn + sA + 2048) = VR1;                                 \
        }                                                                     \
        if ((T) + 3 < 32) {                                                   \
            const int kv = ((T) + 3) * 64;                                    \
            KR0 = *(const bf16x8*)(K + baseQK + (size_t)(kv + r0) * HD + c0); \
            KR1 = *(const bf16x8*)(K + baseQK + (size_t)(kv + r0 + 32) * HD + c0); \
            VR0 = *(const bf16x8*)(Vt + baseV + (size_t)r0 * SEQ + kv + c0);  \
            VR1 = *(const bf16x8*)(Vt + baseV + (size_t)(r0 + 32) * SEQ + kv + c0); \
        }                                                                     \
        const bf16_t* Kb = Ks[(BUF)];                                         \
        const bf16_t* Vb = Vs[(BUF)];                                         \
        f32x4 sf[4];                                                          \
        _Pragma("unroll")                                                     \
        for (int jt = 0; jt < 4; ++jt) sf[jt] = f32x4{0.f, 0.f, 0.f, 0.f};    \
        __builtin_amdgcn_s_setprio(1);                                        \
        _Pragma("unroll")                                                     \
        for (int ks = 0; ks < 2; ++ks) {                                      \
            const int ko = (ks * 32 + quad * 8) ^ cx;                         \
            _Pragma("unroll")                                                 \
            for (int jt = 0; jt < 4; ++jt) {                                  \
                const bf16x8 a = *(const bf16x8*)(Kb + ((jt * 16 + l15) << 6) + ko); \
                sf[jt] = mfma16(a, qf[ks], sf[jt]);                           \
            }                                                                 \
        }                                                                     \
        __builtin_amdgcn_s_setprio(0);                                        \
        u32 w0[4], w1[4];                                                     \
        _Pragma("unroll")                                                     \
        for (int jt = 0; jt < 4; ++jt) {                                      \
            _Pragma("unroll")                                                 \
            for (int i = 0; i < 4; ++i) sf[jt][i] = fast_exp2(sf[jt][i]);     \
            lacc += sf[jt];                                                   \
            w0[jt] = cvtpk_bf16(sf[jt][0], sf[jt][1]);                        \
            w1[jt] = cvtpk_bf16(sf[jt][2], sf[jt][3]);                        \
        }                                                                     \
        swap32(w0[0], w0[1]); swap16(w0[0], w0[1]);                           \
        swap32(w1[0], w1[1]); swap16(w1[0], w1[1]);                           \
        swap32(w0[2], w0[3]); swap16(w0[2], w0[3]);                           \
        swap32(w1[2], w1[3]); swap16(w1[2], w1[3]);                           \
        const u32x4 pq0 = u32x4{w0[0], w1[0], w0[1], w1[1]};                  \
        const u32x4 pq1 = u32x4{w0[2], w1[2], w0[3], w1[3]};                  \
        const bf16x8 pa0 = __builtin_bit_cast(bf16x8, pq0);                   \
        const bf16x8 pa1 = __builtin_bit_cast(bf16x8, pq1);                   \
        __builtin_amdgcn_s_setprio(1);                                        \
        _Pragma("unroll")                                                     \
        for (int c = 0; c < 2; ++c) {                                         \
            const int ko = (c * 32 + quad * 8) ^ cx;                          \
            const bf16x8 pa = c ? pa1 : pa0;                                  \
            _Pragma("unroll")                                                 \
            for (int nt = 0; nt < 4; ++nt) {                                  \
                const bf16x8 b = *(const bf16x8*)(Vb + ((nt * 16 + l15) << 6) + ko); \
                oacc[nt] = mfma16(pa, b, oacc[nt]);                           \
            }                                                                 \
        }                                                                     \
        __builtin_amdgcn_s_setprio(0);                                        \
        if ((T) < 31) barrier_nodrain();                                      \
    } while (0)

__global__ __launch_bounds__(256, 4)
void flash_attn_kernel(const bf16_t* __restrict__ Q,
                       const bf16_t* __restrict__ K,
                       const bf16_t* __restrict__ Vt,
                       bf16_t* __restrict__ Og)
{
    __shared__ __align__(16) bf16_t Ks[2][64 * 64];
    __shared__ __align__(16) bf16_t Vs[2][64 * 64];

    const int tid  = threadIdx.x;
    const int lane = tid & 63, w = tid >> 6, quad = lane >> 4, l15 = lane & 15;
    const int bh = blockIdx.y;
    const int q0 = blockIdx.x * 64;
    const size_t baseQK = (size_t)bh * SEQ * HD;
    const size_t baseV  = (size_t)bh * HD * SEQ;
    const int wm = w * 16;
    const int cx = (l15 & 7) << 3;

    bf16x8 qf[2];
#pragma unroll
    for (int ks = 0; ks < 2; ++ks)
        qf[ks] = *(const bf16x8*)(Q + baseQK + (size_t)(q0 + wm + l15) * HD + ks * 32 + quad * 8);

    f32x4 lacc = f32x4{0.f, 0.f, 0.f, 0.f};
    f32x4 oacc[4];
#pragma unroll
    for (int nt = 0; nt < 4; ++nt) oacc[nt] = f32x4{0.f, 0.f, 0.f, 0.f};

    const int r0 = tid >> 3, c0 = (tid & 7) * 8;
    const int sA = (r0 << 6) + (c0 ^ ((r0 & 7) << 3));

    bf16x8 kA0, kA1, vA0, vA1;
    bf16x8 kB0, kB1, vB0, vB1;

    kA0 = *(const bf16x8*)(K + baseQK + (size_t)r0 * HD + c0);
    kA1 = *(const bf16x8*)(K + baseQK + (size_t)(r0 + 32) * HD + c0);
    vA0 = *(const bf16x8*)(Vt + baseV + (size_t)r0 * SEQ + c0);
    vA1 = *(const bf16x8*)(Vt + baseV + (size_t)(r0 + 32) * SEQ + c0);
    *(bf16x8*)(Ks[0] + sA)        = kA0;
    *(bf16x8*)(Ks[0] + sA + 2048) = kA1;
    *(bf16x8*)(Vs[0] + sA)        = vA0;
    *(bf16x8*)(Vs[0] + sA + 2048) = vA1;
    kB0 = *(const bf16x8*)(K + baseQK + (size_t)(64 + r0) * HD + c0);
    kB1 = *(const bf16x8*)(K + baseQK + (size_t)(64 + r0 + 32) * HD + c0);
    vB0 = *(const bf16x8*)(Vt + baseV + (size_t)r0 * SEQ + 64 + c0);
    vB1 = *(const bf16x8*)(Vt + baseV + (size_t)(r0 + 32) * SEQ + 64 + c0);
    kA0 = *(const bf16x8*)(K + baseQK + (size_t)(128 + r0) * HD + c0);
    kA1 = *(const bf16x8*)(K + baseQK + (size_t)(128 + r0 + 32) * HD + c0);
    vA0 = *(const bf16x8*)(Vt + baseV + (size_t)r0 * SEQ + 128 + c0);
    vA1 = *(const bf16x8*)(Vt + baseV + (size_t)(r0 + 32) * SEQ + 128 + c0);
    barrier_nodrain();

#pragma unroll 1
    for (int tt = 0; tt < 32; tt += 2) {
        FA_ITER(tt,     0, kB0, kB1, vB0, vB1);
        FA_ITER(tt + 1, 1, kA0, kA1, vA0, vA1);
    }

    const int bidx = bh >> 3, h = bh & 7;
    float rs = (lacc[0] + lacc[1]) + (lacc[2] + lacc[3]);
    rs += __shfl_xor(rs, 16);
    rs += __shfl_xor(rs, 32);
    float lf[4];
#pragma unroll
    for (int i = 0; i < 4; ++i)
        lf[i] = __shfl(rs, (lane & 48) | (quad * 4 + i));
#pragma unroll
    for (int nt = 0; nt < 4; ++nt)
#pragma unroll
        for (int i = 0; i < 4; ++i) {
            const int s = q0 + wm + quad * 4 + i;
            const int d = nt * 16 + l15;
            Og[((size_t)(bidx * SEQ + s)) * EMBED + h * HD + d] =
                (bf16_t)(oacc[nt][i] / lf[i]);
        }
}

extern "C" void kernel_launch(void* const* d_in, const int* in_sizes, int n_in,
                              void* d_out, int out_size, void* d_ws, size_t ws_size,
                              hipStream_t stream)
{
    const float* x  = (const float*)d_in[0];
    const float* Wq = (const float*)d_in[1];
    const float* bq = (const float*)d_in[2];
    const float* Wk = (const float*)d_in[3];
    const float* bk = (const float*)d_in[4];
    const float* Wv = (const float*)d_in[5];
    const float* bv = (const float*)d_in[6];
    const float* Wo = (const float*)d_in[7];
    const float* bo = (const float*)d_in[8];
    float* out = (float*)d_out;

    const size_t NE = (size_t)MTOT * EMBED;   // 4,194,304 elems
    // Layout (R8/R11): Qw in d_out's 2nd half (dead before final fp32 out
    // overwrite); Kw / Vtw / Ow in ws. Convert fused into the QKV GEMM.
    bf16_t* Qw  = (bf16_t*)d_out + NE;
    bf16_t* Kw  = (bf16_t*)d_ws;
    bf16_t* Vtw = Kw + NE;
    bf16_t* Ow  = Vtw + NE;

    gemm_gelu_kernel<0, 128><<<dim3(64, 12), 256, 0, stream>>>(
        x, Wq, Wk, Wv, bq, bk, bv, Qw, Kw, Vtw, nullptr);
    flash_attn_kernel<<<dim3(32, 32), 256, 0, stream>>>(Qw, Kw, Vtw, Ow);
    gemm_gelu_kernel<1, 64><<<dim3(64, 8), 256, 0, stream>>>(
        Ow, Wo, nullptr, nullptr, bo, nullptr, nullptr,
        nullptr, nullptr, nullptr, out);
}

// Round 13
// 169.301 us; speedup vs baseline: 1.0571x; 1.0571x over previous
//
#include <hip/hip_runtime.h>
#include <hip/hip_bf16.h>

typedef __bf16 bf16_t;
typedef __bf16 bf16x4 __attribute__((ext_vector_type(4)));
typedef __bf16 bf16x8 __attribute__((ext_vector_type(8)));
typedef float  f32x4  __attribute__((ext_vector_type(4)));
typedef float  f32x8  __attribute__((ext_vector_type(8)));
typedef unsigned int u32;
typedef u32 u32x4 __attribute__((ext_vector_type(4)));

#define EMBED 512
#define NH    8
#define HD    64
#define SEQ   2048
#define MTOT  8192
#define SCQ   0.18033688011112042f   // log2(e) / sqrt(64), folded into Q

__device__ __forceinline__ float gelu_f(float x) {
    return 0.5f * x * (1.0f + erff(x * 0.7071067811865475f));
}

__device__ __forceinline__ f32x4 mfma16(bf16x8 a, bf16x8 b, f32x4 c) {
    return __builtin_amdgcn_mfma_f32_16x16x32_bf16(a, b, c, 0, 0, 0);
}

// Raw barrier: LDS-write visibility only (lgkmcnt(0)), NO vmcnt drain —
// global prefetch loads stay in flight across the barrier; the compiler
// emits counted vmcnt waits at the dependent use.
__device__ __forceinline__ void barrier_nodrain() {
    asm volatile("s_waitcnt lgkmcnt(0)" ::: "memory");
    __builtin_amdgcn_s_barrier();
    asm volatile("" ::: "memory");
}

// Single-instruction exp2 (R10/R11-proven: flash 68.4 -> 52 µs; scores are
// O(1) so no libm range fixup needed).
__device__ __forceinline__ float fast_exp2(float x) {
    float r;
    asm("v_exp_f32 %0, %1" : "=v"(r) : "v"(x));
    return r;
}

// T12 primitives (flash): pack 2 f32 -> 2 bf16, cross-lane register swaps.
__device__ __forceinline__ u32 cvtpk_bf16(float lo, float hi) {
    u32 r;
    asm("v_cvt_pk_bf16_f32 %0, %1, %2" : "=v"(r) : "v"(lo), "v"(hi));
    return r;
}
__device__ __forceinline__ void swap32(u32& a, u32& b) {
    asm volatile("v_permlane32_swap_b32 %0, %1" : "+v"(a), "+v"(b));
}
__device__ __forceinline__ void swap16(u32& a, u32& b) {
    asm volatile("v_permlane16_swap_b32 %0, %1" : "+v"(a), "+v"(b));
}

// ---------------------------------------------------------------------------
// GEMM + bias + GELU.  C[m][n] = gelu( sum_k X[m][k]*W[n][k] + bias[n] )
//
// R13 = R11 structure (the 168.6 session best: reg-staging, padded-72 LDS,
// nodrain barriers, (256,3) — R12's ping-pong@2/CU REVERTED, −10 µs) with
// ONE change: W is register-prefetched across the barrier like A.
// Mechanism: R11's inline-W path (load f32x8 -> ds_write same phase) puts
// a full L2/HBM latency stall on the serial chain EVERY K-step (first
// ds_write waits vmcnt for loads issued instants earlier). R5<->R8 A/B
// bounds this cost at ~5 µs (R5's prefetched-W GEMM was ~5 µs faster than
// R8's inline-W body). Prefetching W one K-step ahead moves its vmcnt-wait
// a full compute phase away. Cost: +32 VGPRs live across the barrier
// (~160-175 total at the ~170 cap for 3 waves/SIMD — spill risk accepted
// as the experiment; VGPR counter is the tripwire).
// ---------------------------------------------------------------------------
template<int MODE, int NTILE>
__global__ __launch_bounds__(256, 3)
void gemm_gelu_kernel(const void*  __restrict__ Xp,
                      const float* __restrict__ W0, const float* __restrict__ W1,
                      const float* __restrict__ W2,
                      const float* __restrict__ Bq, const float* __restrict__ Bk,
                      const float* __restrict__ Bv,
                      bf16_t* __restrict__ O0, bf16_t* __restrict__ O1,
                      bf16_t* __restrict__ O2, float* __restrict__ Of)
{
    constexpr int NTN = NTILE / 32;   // B-staging iters/thr
    __shared__ __align__(16) bf16_t As[128 * 72];
    __shared__ __align__(16) bf16_t Bs[NTILE * 72];
    const int tid  = threadIdx.x;
    const int lane = tid & 63, w = tid >> 6, quad = lane >> 4, l15 = lane & 15;
    const int m0 = blockIdx.x * 128;
    int mat, n0;
    if (MODE == 0) { mat = blockIdx.y >> 2; n0 = (blockIdx.y & 3) * NTILE; }
    else           { mat = 0;               n0 = blockIdx.y * NTILE; }
    const float* W  = (MODE == 0) ? (mat == 0 ? W0 : (mat == 1 ? W1 : W2)) : W0;
    const float* Bi = (MODE == 1) ? Bq : (mat == 0 ? Bq : (mat == 1 ? Bk : Bv));
    const float*  Xf = (const float*)Xp;    // MODE 0
    const bf16_t* Xb = (const bf16_t*)Xp;   // MODE 1

    const int wr = (w >> 1) * 64;            // wave row offset
    const int wc = (w & 1) * (NTILE / 2);    // wave col offset

    const int srow = tid >> 3, scol = (tid & 7) * 8;

    f32x4 acc[4][NTN];
#pragma unroll
    for (int a = 0; a < 4; ++a)
#pragma unroll
        for (int b = 0; b < NTN; ++b) acc[a][b] = f32x4{0.f, 0.f, 0.f, 0.f};

    f32x8  xpf[4];   // MODE 0 A prefetch (fp32)
    bf16x8 xpb[4];   // MODE 1 A prefetch (bf16)
    f32x8  wpf[NTN]; // W prefetch (fp32) — NEW in R13: lives across barrier

    // prologue: A and W tile 0 -> regs
#pragma unroll
    for (int it = 0; it < 4; ++it) {
        const size_t r = (size_t)(m0 + it * 32 + srow);
        if (MODE == 0) xpf[it] = *(const f32x8*)(Xf + r * EMBED + scol);
        else           xpb[it] = *(const bf16x8*)(Xb + r * EMBED + scol);
    }
#pragma unroll
    for (int it = 0; it < NTN; ++it) {
        const int r = it * 32 + srow;
        wpf[it] = *(const f32x8*)(W + (size_t)(n0 + r) * EMBED + scol);
    }

#pragma unroll 1
    for (int kt = 0; kt < 8; ++kt) {
        barrier_nodrain();   // readers of As/Bs (iter kt-1) are done
        // A: write prefetched regs (convert if fp32)
#pragma unroll
        for (int it = 0; it < 4; ++it) {
            if (MODE == 0)
                *(bf16x8*)(As + (it * 32 + srow) * 72 + scol) =
                    __builtin_convertvector(xpf[it], bf16x8);
            else
                *(bf16x8*)(As + (it * 32 + srow) * 72 + scol) = xpb[it];
        }
        // W: write prefetched regs (convert) — vmcnt wait is for loads
        // issued one full K-step ago (hidden under kt-1's compute)
#pragma unroll
        for (int it = 0; it < NTN; ++it) {
            const int r = it * 32 + srow;
            *(bf16x8*)(Bs + r * 72 + scol) =
                __builtin_convertvector(wpf[it], bf16x8);
        }
        // prefetch tile kt+1 (A and W)
        if (kt < 7) {
            const int k1 = (kt + 1) * 64;
#pragma unroll
            for (int it = 0; it < 4; ++it) {
                const size_t r = (size_t)(m0 + it * 32 + srow);
                if (MODE == 0) xpf[it] = *(const f32x8*)(Xf + r * EMBED + k1 + scol);
                else           xpb[it] = *(const bf16x8*)(Xb + r * EMBED + k1 + scol);
            }
#pragma unroll
            for (int it = 0; it < NTN; ++it) {
                const int r = it * 32 + srow;
                wpf[it] = *(const f32x8*)(W + (size_t)(n0 + r) * EMBED + k1 + scol);
            }
        }
        barrier_nodrain();   // As/Bs writes visible to all waves
#pragma unroll
        for (int ks = 0; ks < 2; ++ks) {
            const int ko = (ks * 4 + quad) * 8;
            bf16x8 av[4], bv[NTN];
#pragma unroll
            for (int mt = 0; mt < 4; ++mt)
                av[mt] = *(const bf16x8*)(As + (wr + mt * 16 + l15) * 72 + ko);
#pragma unroll
            for (int nt = 0; nt < NTN; ++nt)
                bv[nt] = *(const bf16x8*)(Bs + (wc + nt * 16 + l15) * 72 + ko);
#pragma unroll
            for (int mt = 0; mt < 4; ++mt)
#pragma unroll
                for (int nt = 0; nt < NTN; ++nt)
                    acc[mt][nt] = mfma16(av[mt], bv[nt], acc[mt][nt]);
        }
    }

    // epilogue (C/D layout: col=l15, row=quad*4+i)
    float biasv[NTN];
#pragma unroll
    for (int nt = 0; nt < NTN; ++nt)
        biasv[nt] = Bi[n0 + wc + nt * 16 + l15];
#pragma unroll
    for (int mt = 0; mt < 4; ++mt) {
        const int mb = m0 + wr + mt * 16 + quad * 4;
        const int bb = mb >> 11, s0 = mb & (SEQ - 1);
#pragma unroll
        for (int nt = 0; nt < NTN; ++nt) {
            const int fc = n0 + wc + nt * 16 + l15;
            const int h = fc >> 6, d = fc & 63;
            float vv[4];
#pragma unroll
            for (int i = 0; i < 4; ++i) vv[i] = gelu_f(acc[mt][nt][i] + biasv[nt]);
            if (MODE == 1) {
#pragma unroll
                for (int i = 0; i < 4; ++i) Of[(size_t)(mb + i) * EMBED + fc] = vv[i];
            } else if (mat == 0) {
#pragma unroll
                for (int i = 0; i < 4; ++i)
                    O0[(((size_t)(bb * NH + h)) * SEQ + s0 + i) * HD + d] = (bf16_t)(vv[i] * SCQ);
            } else if (mat == 1) {
#pragma unroll
                for (int i = 0; i < 4; ++i)
                    O1[(((size_t)(bb * NH + h)) * SEQ + s0 + i) * HD + d] = (bf16_t)vv[i];
            } else {
                bf16x4 pk;
#pragma unroll
                for (int i = 0; i < 4; ++i) pk[i] = (bf16_t)vv[i];
                *(bf16x4*)(O2 + ((size_t)(bb * NH + h) * HD + d) * SEQ + s0) = pk;
            }
        }
    }
}

// ---------------------------------------------------------------------------
// Flash attention — UNCHANGED from R11/R12 (51.8-52.6 µs stable, conflicts
// 0, T12 in-reg P, fast_exp2, nodrain barriers, 2-tile-deep reg prefetch).
// ---------------------------------------------------------------------------
#define FA_ITER(T, BUF, KR0, KR1, VR0, VR1)                                   \
    do {                                                                      \
        if ((T) + 1 < 32) {                                                   \
            bf16_t* Kn = Ks[(BUF) ^ 1];                                       \
            bf16_t* Vn = Vs[(BUF) ^ 1];                                       \
            *(bf16x8*)(Kn + sA)        = KR0;                                 \
            *(bf16x8*)(Kn + sA + 2048) = KR1;                                 \
            *(bf16x8*)(Vn + sA)        = VR0;                                 \
            *(bf16x8*)(Vn + sA + 2048) = VR1;                                 \
        }                                                                     \
        if ((T) + 3 < 32) {                                                   \
            const int kv = ((T) + 3) * 64;                                    \
            KR0 = *(const bf16x8*)(K + baseQK + (size_t)(kv + r0) * HD + c0); \
            KR1 = *(const bf16x8*)(K + baseQK + (size_t)(kv + r0 + 32) * HD + c0); \
            VR0 = *(const bf16x8*)(Vt + baseV + (size_t)r0 * SEQ + kv + c0);  \
            VR1 = *(const bf16x8*)(Vt + baseV + (size_t)(r0 + 32) * SEQ + kv + c0); \
        }                                                                     \
        const bf16_t* Kb = Ks[(BUF)];                                         \
        const bf16_t* Vb = Vs[(BUF)];                                         \
        f32x4 sf[4];                                                          \
        _Pragma("unroll")                                                     \
        for (int jt = 0; jt < 4; ++jt) sf[jt] = f32x4{0.f, 0.f, 0.f, 0.f};    \
        __builtin_amdgcn_s_setprio(1);                                        \
        _Pragma("unroll")                                                     \
        for (int ks = 0; ks < 2; ++ks) {                                      \
            const int ko = (ks * 32 + quad * 8) ^ cx;                         \
            _Pragma("unroll")                                                 \
            for (int jt = 0; jt < 4; ++jt) {                                  \
                const bf16x8 a = *(const bf16x8*)(Kb + ((jt * 16 + l15) << 6) + ko); \
                sf[jt] = mfma16(a, qf[ks], sf[jt]);                           \
            }                                                                 \
        }                                                                     \
        __builtin_amdgcn_s_setprio(0);                                        \
        u32 w0[4], w1[4];                                                     \
        _Pragma("unroll")                                                     \
        for (int jt = 0; jt < 4; ++jt) {                                      \
            _Pragma("unroll")                                                 \
            for (int i = 0; i < 4; ++i) sf[jt][i] = fast_exp2(sf[jt][i]);     \
            lacc += sf[jt];                                                   \
            w0[jt] = cvtpk_bf16(sf[jt][0], sf[jt][1]);                        \
            w1[jt] = cvtpk_bf16(sf[jt][2], sf[jt][3]);                        \
        }                                                                     \
        swap32(w0[0], w0[1]); swap16(w0[0], w0[1]);                           \
        swap32(w1[0], w1[1]); swap16(w1[0], w1[1]);                           \
        swap32(w0[2], w0[3]); swap16(w0[2], w0[3]);                           \
        swap32(w1[2], w1[3]); swap16(w1[2], w1[3]);                           \
        const u32x4 pq0 = u32x4{w0[0], w1[0], w0[1], w1[1]};                  \
        const u32x4 pq1 = u32x4{w0[2], w1[2], w0[3], w1[3]};                  \
        const bf16x8 pa0 = __builtin_bit_cast(bf16x8, pq0);                   \
        const bf16x8 pa1 = __builtin_bit_cast(bf16x8, pq1);                   \
        __builtin_amdgcn_s_setprio(1);                                        \
        _Pragma("unroll")                                                     \
        for (int c = 0; c < 2; ++c) {                                         \
            const int ko = (c * 32 + quad * 8) ^ cx;                          \
            const bf16x8 pa = c ? pa1 : pa0;                                  \
            _Pragma("unroll")                                                 \
            for (int nt = 0; nt < 4; ++nt) {                                  \
                const bf16x8 b = *(const bf16x8*)(Vb + ((nt * 16 + l15) << 6) + ko); \
                oacc[nt] = mfma16(pa, b, oacc[nt]);                           \
            }                                                                 \
        }                                                                     \
        __builtin_amdgcn_s_setprio(0);                                        \
        if ((T) < 31) barrier_nodrain();                                      \
    } while (0)

__global__ __launch_bounds__(256, 4)
void flash_attn_kernel(const bf16_t* __restrict__ Q,
                       const bf16_t* __restrict__ K,
                       const bf16_t* __restrict__ Vt,
                       bf16_t* __restrict__ Og)
{
    __shared__ __align__(16) bf16_t Ks[2][64 * 64];
    __shared__ __align__(16) bf16_t Vs[2][64 * 64];

    const int tid  = threadIdx.x;
    const int lane = tid & 63, w = tid >> 6, quad = lane >> 4, l15 = lane & 15;
    const int bh = blockIdx.y;
    const int q0 = blockIdx.x * 64;
    const size_t baseQK = (size_t)bh * SEQ * HD;
    const size_t baseV  = (size_t)bh * HD * SEQ;
    const int wm = w * 16;
    const int cx = (l15 & 7) << 3;

    bf16x8 qf[2];
#pragma unroll
    for (int ks = 0; ks < 2; ++ks)
        qf[ks] = *(const bf16x8*)(Q + baseQK + (size_t)(q0 + wm + l15) * HD + ks * 32 + quad * 8);

    f32x4 lacc = f32x4{0.f, 0.f, 0.f, 0.f};
    f32x4 oacc[4];
#pragma unroll
    for (int nt = 0; nt < 4; ++nt) oacc[nt] = f32x4{0.f, 0.f, 0.f, 0.f};

    const int r0 = tid >> 3, c0 = (tid & 7) * 8;
    const int sA = (r0 << 6) + (c0 ^ ((r0 & 7) << 3));

    bf16x8 kA0, kA1, vA0, vA1;
    bf16x8 kB0, kB1, vB0, vB1;

    kA0 = *(const bf16x8*)(K + baseQK + (size_t)r0 * HD + c0);
    kA1 = *(const bf16x8*)(K + baseQK + (size_t)(r0 + 32) * HD + c0);
    vA0 = *(const bf16x8*)(Vt + baseV + (size_t)r0 * SEQ + c0);
    vA1 = *(const bf16x8*)(Vt + baseV + (size_t)(r0 + 32) * SEQ + c0);
    *(bf16x8*)(Ks[0] + sA)        = kA0;
    *(bf16x8*)(Ks[0] + sA + 2048) = kA1;
    *(bf16x8*)(Vs[0] + sA)        = vA0;
    *(bf16x8*)(Vs[0] + sA + 2048) = vA1;
    kB0 = *(const bf16x8*)(K + baseQK + (size_t)(64 + r0) * HD + c0);
    kB1 = *(const bf16x8*)(K + baseQK + (size_t)(64 + r0 + 32) * HD + c0);
    vB0 = *(const bf16x8*)(Vt + baseV + (size_t)r0 * SEQ + 64 + c0);
    vB1 = *(const bf16x8*)(Vt + baseV + (size_t)(r0 + 32) * SEQ + 64 + c0);
    kA0 = *(const bf16x8*)(K + baseQK + (size_t)(128 + r0) * HD + c0);
    kA1 = *(const bf16x8*)(K + baseQK + (size_t)(128 + r0 + 32) * HD + c0);
    vA0 = *(const bf16x8*)(Vt + baseV + (size_t)r0 * SEQ + 128 + c0);
    vA1 = *(const bf16x8*)(Vt + baseV + (size_t)(r0 + 32) * SEQ + 128 + c0);
    barrier_nodrain();

#pragma unroll 1
    for (int tt = 0; tt < 32; tt += 2) {
        FA_ITER(tt,     0, kB0, kB1, vB0, vB1);
        FA_ITER(tt + 1, 1, kA0, kA1, vA0, vA1);
    }

    const int bidx = bh >> 3, h = bh & 7;
    float rs = (lacc[0] + lacc[1]) + (lacc[2] + lacc[3]);
    rs += __shfl_xor(rs, 16);
    rs += __shfl_xor(rs, 32);
    float lf[4];
#pragma unroll
    for (int i = 0; i < 4; ++i)
        lf[i] = __shfl(rs, (lane & 48) | (quad * 4 + i));
#pragma unroll
    for (int nt = 0; nt < 4; ++nt)
#pragma unroll
        for (int i = 0; i < 4; ++i) {
            const int s = q0 + wm + quad * 4 + i;
            const int d = nt * 16 + l15;
            Og[((size_t)(bidx * SEQ + s)) * EMBED + h * HD + d] =
                (bf16_t)(oacc[nt][i] / lf[i]);
        }
}

extern "C" void kernel_launch(void* const* d_in, const int* in_sizes, int n_in,
                              void* d_out, int out_size, void* d_ws, size_t ws_size,
                              hipStream_t stream)
{
    const float* x  = (const float*)d_in[0];
    const float* Wq = (const float*)d_in[1];
    const float* bq = (const float*)d_in[2];
    const float* Wk = (const float*)d_in[3];
    const float* bk = (const float*)d_in[4];
    const float* Wv = (const float*)d_in[5];
    const float* bv = (const float*)d_in[6];
    const float* Wo = (const float*)d_in[7];
    const float* bo = (const float*)d_in[8];
    float* out = (float*)d_out;

    const size_t NE = (size_t)MTOT * EMBED;   // 4,194,304 elems
    // Layout (R8/R11): Qw in d_out's 2nd half (dead before final fp32 out
    // overwrite); Kw / Vtw / Ow in ws. Convert fused into the QKV GEMM.
    bf16_t* Qw  = (bf16_t*)d_out + NE;
    bf16_t* Kw  = (bf16_t*)d_ws;
    bf16_t* Vtw = Kw + NE;
    bf16_t* Ow  = Vtw + NE;

    gemm_gelu_kernel<0, 128><<<dim3(64, 12), 256, 0, stream>>>(
        x, Wq, Wk, Wv, bq, bk, bv, Qw, Kw, Vtw, nullptr);
    flash_attn_kernel<<<dim3(32, 32), 256, 0, stream>>>(Qw, Kw, Vtw, Ow);
    gemm_gelu_kernel<1, 64><<<dim3(64, 8), 256, 0, stream>>>(
        Ow, Wo, nullptr, nullptr, bo, nullptr, nullptr,
        nullptr, nullptr, nullptr, out);
}

// Round 14
// 167.044 us; speedup vs baseline: 1.0713x; 1.0135x over previous
//
#include <hip/hip_runtime.h>
#include <hip/hip_bf16.h>

typedef __bf16 bf16_t;
typedef __bf16 bf16x4 __attribute__((ext_vector_type(4)));
typedef __bf16 bf16x8 __attribute__((ext_vector_type(8)));
typedef float  f32x4  __attribute__((ext_vector_type(4)));
typedef float  f32x8  __attribute__((ext_vector_type(8)));
typedef unsigned int u32;
typedef u32 u32x4 __attribute__((ext_vector_type(4)));

#define EMBED 512
#define NH    8
#define HD    64
#define SEQ   2048
#define MTOT  8192
#define SCQ   0.18033688011112042f   // log2(e) / sqrt(64), folded into Q

__device__ __forceinline__ float gelu_f(float x) {
    return 0.5f * x * (1.0f + erff(x * 0.7071067811865475f));
}

__device__ __forceinline__ f32x4 mfma16(bf16x8 a, bf16x8 b, f32x4 c) {
    return __builtin_amdgcn_mfma_f32_16x16x32_bf16(a, b, c, 0, 0, 0);
}

// Raw barrier: LDS-write visibility only (lgkmcnt(0)), NO vmcnt drain —
// global prefetch loads stay in flight across the barrier; the compiler
// emits counted vmcnt waits at the dependent use.
__device__ __forceinline__ void barrier_nodrain() {
    asm volatile("s_waitcnt lgkmcnt(0)" ::: "memory");
    __builtin_amdgcn_s_barrier();
    asm volatile("" ::: "memory");
}

// Single-instruction exp2 (R10/R11-proven: flash 68.4 -> 52 µs; scores are
// O(1) so no libm range fixup needed).
__device__ __forceinline__ float fast_exp2(float x) {
    float r;
    asm("v_exp_f32 %0, %1" : "=v"(r) : "v"(x));
    return r;
}

// T12 primitives (flash): pack 2 f32 -> 2 bf16, cross-lane register swaps.
__device__ __forceinline__ u32 cvtpk_bf16(float lo, float hi) {
    u32 r;
    asm("v_cvt_pk_bf16_f32 %0, %1, %2" : "=v"(r) : "v"(lo), "v"(hi));
    return r;
}
__device__ __forceinline__ void swap32(u32& a, u32& b) {
    asm volatile("v_permlane32_swap_b32 %0, %1" : "+v"(a), "+v"(b));
}
__device__ __forceinline__ void swap16(u32& a, u32& b) {
    asm volatile("v_permlane16_swap_b32 %0, %1" : "+v"(a), "+v"(b));
}

// ---------------------------------------------------------------------------
// GEMM + bias + GELU.  C[m][n] = gelu( sum_k X[m][k]*W[n][k] + bias[n] )
//
// R14 = R13 body (reg-staging, padded-72 LDS, nodrain barriers, A+W
// register prefetch across the barrier, fused fp32 convert, (256,3))
// with MTILE as a template parameter:
//  - MODE 0 (QKV): <0,128,128>, grid(64,12) — BIT-IDENTICAL to R13.
//  - MODE 1 (out): <1,64,64>, grid(128,8) = 1024 blocks, LDS 18.4KB ->
//    4 blocks/CU all-concurrent (was 128x64 tile, 512 blocks = 2/CU).
//    Rationale: cross-block co-residency is the session's only
//    positively-signed structural lever (R12: 3->2/CU cost 10 µs); the
//    out-GEMM was the one kernel stuck at 2/CU, with ~40 µs for 4.3 GFLOP.
// ---------------------------------------------------------------------------
template<int MODE, int NTILE, int MTILE>
__global__ __launch_bounds__(256, 3)
void gemm_gelu_kernel(const void*  __restrict__ Xp,
                      const float* __restrict__ W0, const float* __restrict__ W1,
                      const float* __restrict__ W2,
                      const float* __restrict__ Bq, const float* __restrict__ Bk,
                      const float* __restrict__ Bv,
                      bf16_t* __restrict__ O0, bf16_t* __restrict__ O1,
                      bf16_t* __restrict__ O2, float* __restrict__ Of)
{
    constexpr int NTN = NTILE / 32;   // B-staging iters/thr, nt per wave
    constexpr int NTM = MTILE / 32;   // A-staging iters/thr, mt per wave
    __shared__ __align__(16) bf16_t As[MTILE * 72];
    __shared__ __align__(16) bf16_t Bs[NTILE * 72];
    const int tid  = threadIdx.x;
    const int lane = tid & 63, w = tid >> 6, quad = lane >> 4, l15 = lane & 15;
    const int m0 = blockIdx.x * MTILE;
    int mat, n0;
    if (MODE == 0) { mat = blockIdx.y >> 2; n0 = (blockIdx.y & 3) * NTILE; }
    else           { mat = 0;               n0 = blockIdx.y * NTILE; }
    const float* W  = (MODE == 0) ? (mat == 0 ? W0 : (mat == 1 ? W1 : W2)) : W0;
    const float* Bi = (MODE == 1) ? Bq : (mat == 0 ? Bq : (mat == 1 ? Bk : Bv));
    const float*  Xf = (const float*)Xp;    // MODE 0
    const bf16_t* Xb = (const bf16_t*)Xp;   // MODE 1

    const int wr = (w >> 1) * (MTILE / 2);   // wave row offset
    const int wc = (w & 1) * (NTILE / 2);    // wave col offset

    const int srow = tid >> 3, scol = (tid & 7) * 8;

    f32x4 acc[NTM][NTN];
#pragma unroll
    for (int a = 0; a < NTM; ++a)
#pragma unroll
        for (int b = 0; b < NTN; ++b) acc[a][b] = f32x4{0.f, 0.f, 0.f, 0.f};

    f32x8  xpf[NTM];   // MODE 0 A prefetch (fp32)
    bf16x8 xpb[NTM];   // MODE 1 A prefetch (bf16)
    f32x8  wpf[NTN];   // W prefetch (fp32), lives across barrier

    // prologue: A and W tile 0 -> regs
#pragma unroll
    for (int it = 0; it < NTM; ++it) {
        const size_t r = (size_t)(m0 + it * 32 + srow);
        if (MODE == 0) xpf[it] = *(const f32x8*)(Xf + r * EMBED + scol);
        else           xpb[it] = *(const bf16x8*)(Xb + r * EMBED + scol);
    }
#pragma unroll
    for (int it = 0; it < NTN; ++it) {
        const int r = it * 32 + srow;
        wpf[it] = *(const f32x8*)(W + (size_t)(n0 + r) * EMBED + scol);
    }

#pragma unroll 1
    for (int kt = 0; kt < 8; ++kt) {
        barrier_nodrain();   // readers of As/Bs (iter kt-1) are done
        // A: write prefetched regs (convert if fp32)
#pragma unroll
        for (int it = 0; it < NTM; ++it) {
            if (MODE == 0)
                *(bf16x8*)(As + (it * 32 + srow) * 72 + scol) =
                    __builtin_convertvector(xpf[it], bf16x8);
            else
                *(bf16x8*)(As + (it * 32 + srow) * 72 + scol) = xpb[it];
        }
        // W: write prefetched regs (convert) — vmcnt wait is for loads
        // issued one full K-step ago (hidden under kt-1's compute)
#pragma unroll
        for (int it = 0; it < NTN; ++it) {
            const int r = it * 32 + srow;
            *(bf16x8*)(Bs + r * 72 + scol) =
                __builtin_convertvector(wpf[it], bf16x8);
        }
        // prefetch tile kt+1 (A and W)
        if (kt < 7) {
            const int k1 = (kt + 1) * 64;
#pragma unroll
            for (int it = 0; it < NTM; ++it) {
                const size_t r = (size_t)(m0 + it * 32 + srow);
                if (MODE == 0) xpf[it] = *(const f32x8*)(Xf + r * EMBED + k1 + scol);
                else           xpb[it] = *(const bf16x8*)(Xb + r * EMBED + k1 + scol);
            }
#pragma unroll
            for (int it = 0; it < NTN; ++it) {
                const int r = it * 32 + srow;
                wpf[it] = *(const f32x8*)(W + (size_t)(n0 + r) * EMBED + k1 + scol);
            }
        }
        barrier_nodrain();   // As/Bs writes visible to all waves
#pragma unroll
        for (int ks = 0; ks < 2; ++ks) {
            const int ko = (ks * 4 + quad) * 8;
            bf16x8 av[NTM], bv[NTN];
#pragma unroll
            for (int mt = 0; mt < NTM; ++mt)
                av[mt] = *(const bf16x8*)(As + (wr + mt * 16 + l15) * 72 + ko);
#pragma unroll
            for (int nt = 0; nt < NTN; ++nt)
                bv[nt] = *(const bf16x8*)(Bs + (wc + nt * 16 + l15) * 72 + ko);
#pragma unroll
            for (int mt = 0; mt < NTM; ++mt)
#pragma unroll
                for (int nt = 0; nt < NTN; ++nt)
                    acc[mt][nt] = mfma16(av[mt], bv[nt], acc[mt][nt]);
        }
    }

    // epilogue (C/D layout: col=l15, row=quad*4+i)
    float biasv[NTN];
#pragma unroll
    for (int nt = 0; nt < NTN; ++nt)
        biasv[nt] = Bi[n0 + wc + nt * 16 + l15];
#pragma unroll
    for (int mt = 0; mt < NTM; ++mt) {
        const int mb = m0 + wr + mt * 16 + quad * 4;
        const int bb = mb >> 11, s0 = mb & (SEQ - 1);
#pragma unroll
        for (int nt = 0; nt < NTN; ++nt) {
            const int fc = n0 + wc + nt * 16 + l15;
            const int h = fc >> 6, d = fc & 63;
            float vv[4];
#pragma unroll
            for (int i = 0; i < 4; ++i) vv[i] = gelu_f(acc[mt][nt][i] + biasv[nt]);
            if (MODE == 1) {
#pragma unroll
                for (int i = 0; i < 4; ++i) Of[(size_t)(mb + i) * EMBED + fc] = vv[i];
            } else if (mat == 0) {
#pragma unroll
                for (int i = 0; i < 4; ++i)
                    O0[(((size_t)(bb * NH + h)) * SEQ + s0 + i) * HD + d] = (bf16_t)(vv[i] * SCQ);
            } else if (mat == 1) {
#pragma unroll
                for (int i = 0; i < 4; ++i)
                    O1[(((size_t)(bb * NH + h)) * SEQ + s0 + i) * HD + d] = (bf16_t)vv[i];
            } else {
                bf16x4 pk;
#pragma unroll
                for (int i = 0; i < 4; ++i) pk[i] = (bf16_t)vv[i];
                *(bf16x4*)(O2 + ((size_t)(bb * NH + h) * HD + d) * SEQ + s0) = pk;
            }
        }
    }
}

// ---------------------------------------------------------------------------
// Flash attention — UNCHANGED from R11-R13 (51.8-52.6 µs stable, conflicts
// 0, T12 in-reg P, fast_exp2, nodrain barriers, 2-tile-deep reg prefetch).
// ---------------------------------------------------------------------------
#define FA_ITER(T, BUF, KR0, KR1, VR0, VR1)                                   \
    do {                                                                      \
        if ((T) + 1 < 32) {                                                   \
            bf16_t* Kn = Ks[(BUF) ^ 1];                                       \
            bf16_t* Vn = Vs[(BUF) ^ 1];                                       \
            *(bf16x8*)(Kn + sA)        = KR0;                                 \
            *(bf16x8*)(Kn + sA + 2048) = KR1;                                 \
            *(bf16x8*)(Vn + sA)        = VR0;                                 \
            *(bf16x8*)(Vn + sA + 2048) = VR1;                                 \
        }                                                                     \
        if ((T) + 3 < 32) {                                                   \
            const int kv = ((T) + 3) * 64;                                    \
            KR0 = *(const bf16x8*)(K + baseQK + (size_t)(kv + r0) * HD + c0); \
            KR1 = *(const bf16x8*)(K + baseQK + (size_t)(kv + r0 + 32) * HD + c0); \
            VR0 = *(const bf16x8*)(Vt + baseV + (size_t)r0 * SEQ + kv + c0);  \
            VR1 = *(const bf16x8*)(Vt + baseV + (size_t)(r0 + 32) * SEQ + kv + c0); \
        }                                                                     \
        const bf16_t* Kb = Ks[(BUF)];                                         \
        const bf16_t* Vb = Vs[(BUF)];                                         \
        f32x4 sf[4];                                                          \
        _Pragma("unroll")                                                     \
        for (int jt = 0; jt < 4; ++jt) sf[jt] = f32x4{0.f, 0.f, 0.f, 0.f};    \
        __builtin_amdgcn_s_setprio(1);                                        \
        _Pragma("unroll")                                                     \
        for (int ks = 0; ks < 2; ++ks) {                                      \
            const int ko = (ks * 32 + quad * 8) ^ cx;                         \
            _Pragma("unroll")                                                 \
            for (int jt = 0; jt < 4; ++jt) {                                  \
                const bf16x8 a = *(const bf16x8*)(Kb + ((jt * 16 + l15) << 6) + ko); \
                sf[jt] = mfma16(a, qf[ks], sf[jt]);                           \
            }                                                                 \
        }                                                                     \
        __builtin_amdgcn_s_setprio(0);                                        \
        u32 w0[4], w1[4];                                                     \
        _Pragma("unroll")                                                     \
        for (int jt = 0; jt < 4; ++jt) {                                      \
            _Pragma("unroll")                                                 \
            for (int i = 0; i < 4; ++i) sf[jt][i] = fast_exp2(sf[jt][i]);     \
            lacc += sf[jt];                                                   \
            w0[jt] = cvtpk_bf16(sf[jt][0], sf[jt][1]);                        \
            w1[jt] = cvtpk_bf16(sf[jt][2], sf[jt][3]);                        \
        }                                                                     \
        swap32(w0[0], w0[1]); swap16(w0[0], w0[1]);                           \
        swap32(w1[0], w1[1]); swap16(w1[0], w1[1]);                           \
        swap32(w0[2], w0[3]); swap16(w0[2], w0[3]);                           \
        swap32(w1[2], w1[3]); swap16(w1[2], w1[3]);                           \
        const u32x4 pq0 = u32x4{w0[0], w1[0], w0[1], w1[1]};                  \
        const u32x4 pq1 = u32x4{w0[2], w1[2], w0[3], w1[3]};                  \
        const bf16x8 pa0 = __builtin_bit_cast(bf16x8, pq0);                   \
        const bf16x8 pa1 = __builtin_bit_cast(bf16x8, pq1);                   \
        __builtin_amdgcn_s_setprio(1);                                        \
        _Pragma("unroll")                                                     \
        for (int c = 0; c < 2; ++c) {                                         \
            const int ko = (c * 32 + quad * 8) ^ cx;                          \
            const bf16x8 pa = c ? pa1 : pa0;                                  \
            _Pragma("unroll")                                                 \
            for (int nt = 0; nt < 4; ++nt) {                                  \
                const bf16x8 b = *(const bf16x8*)(Vb + ((nt * 16 + l15) << 6) + ko); \
                oacc[nt] = mfma16(pa, b, oacc[nt]);                           \
            }                                                                 \
        }                                                                     \
        __builtin_amdgcn_s_setprio(0);                                        \
        if ((T) < 31) barrier_nodrain();                                      \
    } while (0)

__global__ __launch_bounds__(256, 4)
void flash_attn_kernel(const bf16_t* __restrict__ Q,
                       const bf16_t* __restrict__ K,
                       const bf16_t* __restrict__ Vt,
                       bf16_t* __restrict__ Og)
{
    __shared__ __align__(16) bf16_t Ks[2][64 * 64];
    __shared__ __align__(16) bf16_t Vs[2][64 * 64];

    const int tid  = threadIdx.x;
    const int lane = tid & 63, w = tid >> 6, quad = lane >> 4, l15 = lane & 15;
    const int bh = blockIdx.y;
    const int q0 = blockIdx.x * 64;
    const size_t baseQK = (size_t)bh * SEQ * HD;
    const size_t baseV  = (size_t)bh * HD * SEQ;
    const int wm = w * 16;
    const int cx = (l15 & 7) << 3;

    bf16x8 qf[2];
#pragma unroll
    for (int ks = 0; ks < 2; ++ks)
        qf[ks] = *(const bf16x8*)(Q + baseQK + (size_t)(q0 + wm + l15) * HD + ks * 32 + quad * 8);

    f32x4 lacc = f32x4{0.f, 0.f, 0.f, 0.f};
    f32x4 oacc[4];
#pragma unroll
    for (int nt = 0; nt < 4; ++nt) oacc[nt] = f32x4{0.f, 0.f, 0.f, 0.f};

    const int r0 = tid >> 3, c0 = (tid & 7) * 8;
    const int sA = (r0 << 6) + (c0 ^ ((r0 & 7) << 3));

    bf16x8 kA0, kA1, vA0, vA1;
    bf16x8 kB0, kB1, vB0, vB1;

    kA0 = *(const bf16x8*)(K + baseQK + (size_t)r0 * HD + c0);
    kA1 = *(const bf16x8*)(K + baseQK + (size_t)(r0 + 32) * HD + c0);
    vA0 = *(const bf16x8*)(Vt + baseV + (size_t)r0 * SEQ + c0);
    vA1 = *(const bf16x8*)(Vt + baseV + (size_t)(r0 + 32) * SEQ + c0);
    *(bf16x8*)(Ks[0] + sA)        = kA0;
    *(bf16x8*)(Ks[0] + sA + 2048) = kA1;
    *(bf16x8*)(Vs[0] + sA)        = vA0;
    *(bf16x8*)(Vs[0] + sA + 2048) = vA1;
    kB0 = *(const bf16x8*)(K + baseQK + (size_t)(64 + r0) * HD + c0);
    kB1 = *(const bf16x8*)(K + baseQK + (size_t)(64 + r0 + 32) * HD + c0);
    vB0 = *(const bf16x8*)(Vt + baseV + (size_t)r0 * SEQ + 64 + c0);
    vB1 = *(const bf16x8*)(Vt + baseV + (size_t)(r0 + 32) * SEQ + 64 + c0);
    kA0 = *(const bf16x8*)(K + baseQK + (size_t)(128 + r0) * HD + c0);
    kA1 = *(const bf16x8*)(K + baseQK + (size_t)(128 + r0 + 32) * HD + c0);
    vA0 = *(const bf16x8*)(Vt + baseV + (size_t)r0 * SEQ + 128 + c0);
    vA1 = *(const bf16x8*)(Vt + baseV + (size_t)(r0 + 32) * SEQ + 128 + c0);
    barrier_nodrain();

#pragma unroll 1
    for (int tt = 0; tt < 32; tt += 2) {
        FA_ITER(tt,     0, kB0, kB1, vB0, vB1);
        FA_ITER(tt + 1, 1, kA0, kA1, vA0, vA1);
    }

    const int bidx = bh >> 3, h = bh & 7;
    float rs = (lacc[0] + lacc[1]) + (lacc[2] + lacc[3]);
    rs += __shfl_xor(rs, 16);
    rs += __shfl_xor(rs, 32);
    float lf[4];
#pragma unroll
    for (int i = 0; i < 4; ++i)
        lf[i] = __shfl(rs, (lane & 48) | (quad * 4 + i));
#pragma unroll
    for (int nt = 0; nt < 4; ++nt)
#pragma unroll
        for (int i = 0; i < 4; ++i) {
            const int s = q0 + wm + quad * 4 + i;
            const int d = nt * 16 + l15;
            Og[((size_t)(bidx * SEQ + s)) * EMBED + h * HD + d] =
                (bf16_t)(oacc[nt][i] / lf[i]);
        }
}

extern "C" void kernel_launch(void* const* d_in, const int* in_sizes, int n_in,
                              void* d_out, int out_size, void* d_ws, size_t ws_size,
                              hipStream_t stream)
{
    const float* x  = (const float*)d_in[0];
    const float* Wq = (const float*)d_in[1];
    const float* bq = (const float*)d_in[2];
    const float* Wk = (const float*)d_in[3];
    const float* bk = (const float*)d_in[4];
    const float* Wv = (const float*)d_in[5];
    const float* bv = (const float*)d_in[6];
    const float* Wo = (const float*)d_in[7];
    const float* bo = (const float*)d_in[8];
    float* out = (float*)d_out;

    const size_t NE = (size_t)MTOT * EMBED;   // 4,194,304 elems
    // Layout (R8/R11): Qw in d_out's 2nd half (dead before final fp32 out
    // overwrite); Kw / Vtw / Ow in ws. Convert fused into the QKV GEMM.
    bf16_t* Qw  = (bf16_t*)d_out + NE;
    bf16_t* Kw  = (bf16_t*)d_ws;
    bf16_t* Vtw = Kw + NE;
    bf16_t* Ow  = Vtw + NE;

    gemm_gelu_kernel<0, 128, 128><<<dim3(64, 12), 256, 0, stream>>>(
        x, Wq, Wk, Wv, bq, bk, bv, Qw, Kw, Vtw, nullptr);
    flash_attn_kernel<<<dim3(32, 32), 256, 0, stream>>>(Qw, Kw, Vtw, Ow);
    gemm_gelu_kernel<1, 64, 64><<<dim3(128, 8), 256, 0, stream>>>(
        Ow, Wo, nullptr, nullptr, bo, nullptr, nullptr,
        nullptr, nullptr, nullptr, out);
}